// Round 19
// baseline (1391.698 us; speedup 1.0000x reference)
//
#include <hip/hip_runtime.h>
#include <hip/hip_bf16.h>
#include <stdint.h>

typedef __hip_bfloat16 bf16;
typedef __attribute__((ext_vector_type(8))) short short8;
typedef __attribute__((ext_vector_type(4))) float f32x4;
typedef __attribute__((ext_vector_type(2))) unsigned int uint32x2;

static constexpr int TB = 8;     // batch
static constexpr int TT = 1024;  // seq len
static constexpr int TD = 1024;  // d_model
static constexpr int TH = 16;    // heads
static constexpr int TL = 4;     // layers
static constexpr int TDF = 4096; // ffn dim
static constexpr int TM = TB * TT; // 8192 rows
static constexpr int QS = 3072;  // fused qkv row stride

#if __has_builtin(__builtin_amdgcn_permlane16_swap) && __has_builtin(__builtin_amdgcn_permlane32_swap)
#define USE_PERMLANE 1
#else
#define USE_PERMLANE 0
#endif

#define GLOAD16(g, l) __builtin_amdgcn_global_load_lds( \
    (const __attribute__((address_space(1))) unsigned int*)(g), \
    (__attribute__((address_space(3))) unsigned int*)(l), 16, 0, 0)

// ------------- embedding: xbf = bf16(tok_emb[idx] + pos_emb) -------------
__global__ __launch_bounds__(256) void k_embed(const int* __restrict__ idx,
        const float* __restrict__ tok, const float* __restrict__ pos,
        bf16* __restrict__ xbf) {
    int row = blockIdx.x;            // b*T + t
    int t = row & (TT - 1);
    int token = idx[row];
    int c = threadIdx.x * 4;
    float4 tv = *(const float4*)(tok + (int64_t)token * TD + c);
    float4 pv = *(const float4*)(pos + (int64_t)t * TD + c);
    bf16 t4[4];
    t4[0] = __float2bfloat16(tv.x + pv.x);
    t4[1] = __float2bfloat16(tv.y + pv.y);
    t4[2] = __float2bfloat16(tv.z + pv.z);
    t4[3] = __float2bfloat16(tv.w + pv.w);
    *(uint2*)(xbf + (int64_t)row * TD + c) = *(uint2*)t4;
}

// ---------------- layernorm: bf16 in -> bf16 out ----------------
__global__ __launch_bounds__(256) void k_ln(const bf16* __restrict__ x,
        const float* __restrict__ w, const float* __restrict__ b,
        bf16* __restrict__ out) {
    int row = blockIdx.x;
    int tid = threadIdx.x;
    const bf16* xr = x + (int64_t)row * TD;
    uint2 raw = *(const uint2*)(xr + tid * 4);
    const bf16* rp = (const bf16*)&raw;
    float v0 = __bfloat162float(rp[0]), v1 = __bfloat162float(rp[1]);
    float v2 = __bfloat162float(rp[2]), v3 = __bfloat162float(rp[3]);
    float s  = v0 + v1 + v2 + v3;
    float s2 = v0*v0 + v1*v1 + v2*v2 + v3*v3;
    #pragma unroll
    for (int off = 32; off; off >>= 1) { s += __shfl_xor(s, off); s2 += __shfl_xor(s2, off); }
    __shared__ float red[8];
    int wv_ = tid >> 6, ln_ = tid & 63;
    if (ln_ == 0) { red[wv_] = s; red[4 + wv_] = s2; }
    __syncthreads();
    s  = red[0] + red[1] + red[2] + red[3];
    s2 = red[4] + red[5] + red[6] + red[7];
    float mean = s * (1.f / TD);
    float var  = s2 * (1.f / TD) - mean * mean;
    float rstd = rsqrtf(var + 1e-5f);
    float4 wv4 = *(const float4*)(w + tid * 4);
    float4 bv4 = *(const float4*)(b + tid * 4);
    bf16 t4[4];
    t4[0] = __float2bfloat16((v0 - mean) * rstd * wv4.x + bv4.x);
    t4[1] = __float2bfloat16((v1 - mean) * rstd * wv4.y + bv4.y);
    t4[2] = __float2bfloat16((v2 - mean) * rstd * wv4.z + bv4.z);
    t4[3] = __float2bfloat16((v3 - mean) * rstd * wv4.w + bv4.w);
    *(uint2*)(out + (int64_t)row * TD + tid * 4) = *(uint2*)t4;
}

// ---- fused weight transpose+cvt for ALL layers (one launch) ----
// blockIdx.y = layer; blockIdx.x decodes matrix/tile as before.
__global__ __launch_bounds__(256) void k_wt(
        const float* __restrict__ wq0, const float* __restrict__ wk0,
        const float* __restrict__ wv0, const float* __restrict__ wp0,
        const float* __restrict__ w10, const float* __restrict__ w20,
        bf16* __restrict__ qkvT0, bf16* __restrict__ wpT0,
        bf16* __restrict__ w1T0, bf16* __restrict__ w2T0) {
    __shared__ bf16 tile[64 * 74];
    const int l = blockIdx.y;
    const float* wq = wq0 + (int64_t)l * TD * TD;
    const float* wk = wk0 + (int64_t)l * TD * TD;
    const float* wv = wv0 + (int64_t)l * TD * TD;
    const float* wp = wp0 + (int64_t)l * TD * TD;
    const float* w1 = w10 + (int64_t)l * TD * TDF;
    const float* w2 = w20 + (int64_t)l * TDF * TD;
    bf16* qkvT = qkvT0 + (int64_t)l * 3 * TD * TD;
    bf16* wpT  = wpT0  + (int64_t)l * TD * TD;
    bf16* w1T  = w1T0  + (int64_t)l * TD * TDF;
    bf16* w2T  = w2T0  + (int64_t)l * TDF * TD;
    const int id = blockIdx.x;
    const float* src; bf16* dst; int K, N, n0, k0;
    if (id < 768) {
        int w = id >> 8, r = id & 255;
        src = (w == 0) ? wq : ((w == 1) ? wk : wv);
        dst = qkvT + (int64_t)w * 1024 * 1024;
        K = 1024; N = 1024; n0 = (r & 15) * 64; k0 = (r >> 4) * 64;
    } else if (id < 1024) {
        int r = id - 768; src = wp; dst = wpT;
        K = 1024; N = 1024; n0 = (r & 15) * 64; k0 = (r >> 4) * 64;
    } else if (id < 2048) {
        int r = id - 1024; src = w1; dst = w1T;
        K = 1024; N = 4096; n0 = (r & 63) * 64; k0 = (r >> 6) * 64;
    } else {
        int r = id - 2048; src = w2; dst = w2T;
        K = 4096; N = 1024; n0 = (r & 15) * 64; k0 = (r >> 4) * 64;
    }
    const int tid = threadIdx.x;
    #pragma unroll
    for (int i = 0; i < 16; i++) {
        int q = i * 256 + tid;
        int r = q >> 6, c = q & 63;
        tile[r * 74 + c] = __float2bfloat16(src[(int64_t)(k0 + r) * N + n0 + c]);
    }
    __syncthreads();
    #pragma unroll
    for (int i = 0; i < 16; i++) {
        int q = i * 256 + tid;
        int nr = q >> 6, kc = q & 63;
        dst[(int64_t)(n0 + nr) * K + k0 + kc] = tile[kc * 74 + nr];
    }
}

// ------------- GEMM 256x256 deep-pipelined (T2+T3+T4+T5) -------------
// EPI bits: 1=+bias, 2=relu, 8=fp32 out, 16=QKV mode (V cols >=2048 written
// transposed to vtp as [b][h][64 dims][1024 tokens]).
template<int EPI>
__global__ __launch_bounds__(512, 2) void k_gemm256(const bf16* __restrict__ A,
        const bf16* __restrict__ BT, const float* __restrict__ bias,
        float* __restrict__ outF, bf16* __restrict__ outB,
        bf16* __restrict__ vtp, int M, int N, int K) {
    extern __shared__ __align__(16) char smem[];   // [A0|A1|B0|B1] 32KB each
    const int tid = threadIdx.x;
    const int lane = tid & 63, wave = tid >> 6;
    const int wm = wave >> 2, wn = wave & 3;       // per-wave out: 128x64
    const int lr = lane & 15, lk = lane >> 4;
    const int nb = gridDim.x;                      // % 8 == 0
    const int sb = (blockIdx.x & 7) * (nb >> 3) + (blockIdx.x >> 3);
    const int nbn = N >> 8;
    const int bm = sb / nbn, bn = sb % nbn;
    const int64_t aBase = (int64_t)bm * 256 * K;
    const int64_t bBase = (int64_t)bn * 256 * K;
    const int NT = K >> 6;

    const int tswz = tid ^ (((tid >> 5) & 1) << 1);
    const int row0 = tswz >> 3, s0 = tswz & 7;

#define STAGE256(tt) do { \
        char* Ad_ = smem + (((tt) & 1) << 15); \
        char* Bd_ = smem + 65536 + (((tt) & 1) << 15); \
        _Pragma("unroll") \
        for (int j = 0; j < 4; j++) { \
            const int rr_ = j * 64 + row0; \
            GLOAD16(A  + aBase + (int64_t)rr_ * K + (tt) * 64 + s0 * 8, Ad_ + (j * 512 + tid) * 16); \
            GLOAD16(BT + bBase + (int64_t)rr_ * K + (tt) * 64 + s0 * 8, Bd_ + (j * 512 + tid) * 16); \
        } \
    } while (0)

    f32x4 acc[8][4] = {};
    const int lkx = lk ^ ((lr & 4) >> 1);          // read-side st swizzle
    const int aoff = wm * 8192 + lr * 64 + lkx * 8;
    const int boff = wn * 4096 + lr * 64 + lkx * 8;

    STAGE256(0);
    STAGE256(1);
    asm volatile("s_waitcnt vmcnt(8)" ::: "memory");   // tile 0 landed
    __builtin_amdgcn_s_barrier();

    for (int t = 0; t < NT; ++t) {
        const bf16* Ab = (const bf16*)(smem + ((t & 1) << 15));
        const bf16* Bb = (const bf16*)(smem + 65536 + ((t & 1) << 15));
        short8 af[2][8], bv[2][4];
        #pragma unroll
        for (int kk = 0; kk < 2; kk++) {
            #pragma unroll
            for (int m = 0; m < 8; m++)
                af[kk][m] = *(const short8*)(Ab + aoff + m * 1024 + kk * 32);
            #pragma unroll
            for (int n = 0; n < 4; n++)
                bv[kk][n] = *(const short8*)(Bb + boff + n * 1024 + kk * 32);
        }
        asm volatile("s_waitcnt lgkmcnt(0)" ::: "memory");
        __builtin_amdgcn_sched_barrier(0);
        __builtin_amdgcn_s_barrier();          // all waves done reading buf[t&1]
        if (t + 2 < NT) STAGE256(t + 2);       // overwrite buf[t&1] (now dead)
        __builtin_amdgcn_s_setprio(1);
        #pragma unroll
        for (int kk = 0; kk < 2; kk++)
            #pragma unroll
            for (int fm = 0; fm < 8; fm++)
                #pragma unroll
                for (int fn = 0; fn < 4; fn++)
                    acc[fm][fn] = __builtin_amdgcn_mfma_f32_16x16x32_bf16(
                        af[kk][fm], bv[kk][fn], acc[fm][fn], 0, 0, 0);
        __builtin_amdgcn_s_setprio(0);
        if (t + 2 < NT) {
            asm volatile("s_waitcnt vmcnt(8)" ::: "memory");   // tile t+1 landed
            __builtin_amdgcn_s_barrier();
        } else if (t + 1 < NT) {
            asm volatile("s_waitcnt vmcnt(0)" ::: "memory");   // final drain
            __builtin_amdgcn_s_barrier();
        }
    }
#undef STAGE256

    #pragma unroll
    for (int fm = 0; fm < 8; fm++) {
        #pragma unroll
        for (int fn = 0; fn < 4; fn++) {
            const int col = bn * 256 + wn * 64 + fn * 16 + lr;
            if constexpr (EPI & 16) {
                const int trow = bm * 256 + wm * 128 + fm * 16 + lk * 4;
                if (col >= 2048) {
                    // V column: write transposed vt[b][h][d][t], 4 tokens = 8B
                    const int d = col - 2048;
                    bf16 t4[4];
                    #pragma unroll
                    for (int r = 0; r < 4; r++)
                        t4[r] = __float2bfloat16(acc[fm][fn][r]);
                    const int bb = trow >> 10, tt2 = trow & 1023;
                    *(uint2*)(vtp + ((int64_t)((bb * TH + (d >> 6)) * 64 + (d & 63)) * TT + tt2)) = *(uint2*)t4;
                } else {
                    #pragma unroll
                    for (int r = 0; r < 4; r++)
                        outB[(int64_t)(trow + r) * N + col] = __float2bfloat16(acc[fm][fn][r]);
                }
            } else {
                #pragma unroll
                for (int r = 0; r < 4; r++) {
                    const int row = bm * 256 + wm * 128 + fm * 16 + lk * 4 + r;
                    float v = acc[fm][fn][r];
                    if constexpr (EPI & 1) v += bias[col];
                    if constexpr (EPI & 2) v = fmaxf(v, 0.f);
                    if constexpr (EPI & 8) outF[(int64_t)row * N + col] = v;
                    else outB[(int64_t)row * N + col] = __float2bfloat16(v);
                }
            }
        }
    }
}

// ------------- GEMM 128x128 deep-pipelined (64KB LDS, 2 blocks/CU) -------
// EPI bits: 1=+bias, 2=relu, 4=+bf16 residual, 8=fp32 out (else bf16 out)
template<int EPI>
__global__ __launch_bounds__(512, 2) void k_gemm128d(const bf16* __restrict__ A,
        const bf16* __restrict__ BT, const float* __restrict__ bias,
        const bf16* __restrict__ residB,
        float* __restrict__ outF, bf16* __restrict__ outB, int M, int N, int K) {
    extern __shared__ __align__(16) char smem[];   // A0|A1|B0|B1 = 16KB each
    const int tid = threadIdx.x;
    const int lane = tid & 63, wave = tid >> 6;
    const int wm = wave >> 2, wn = wave & 3;       // 2Mx4N, per-wave 64x32
    const int lr = lane & 15, lk = lane >> 4;
    const int nb = gridDim.x;                      // % 8 == 0
    const int sb = (blockIdx.x & 7) * (nb >> 3) + (blockIdx.x >> 3);
    const int nbn = N >> 7;
    const int bm = sb / nbn, bn = sb % nbn;
    const int64_t aBase = (int64_t)bm * 128 * K;
    const int64_t bBase = (int64_t)bn * 128 * K;
    const int NT = K >> 6;

    const int tswz = tid ^ (((tid >> 5) & 1) << 1);
    const int row0 = tswz >> 3, s0 = tswz & 7;     // rows 0..63, chunk 0..7

#define STAGE128D(tt) do { \
        char* Ad_ = smem + (((tt) & 1) << 14); \
        char* Bd_ = smem + 32768 + (((tt) & 1) << 14); \
        _Pragma("unroll") \
        for (int j = 0; j < 2; j++) { \
            const int rr_ = j * 64 + row0; \
            GLOAD16(A  + aBase + (int64_t)rr_ * K + (tt) * 64 + s0 * 8, Ad_ + (j * 512 + tid) * 16); \
            GLOAD16(BT + bBase + (int64_t)rr_ * K + (tt) * 64 + s0 * 8, Bd_ + (j * 512 + tid) * 16); \
        } \
    } while (0)

    f32x4 acc[4][2] = {};
    const int lkx = lk ^ ((lr & 4) >> 1);          // read-side st swizzle
    const int aoff = wm * 4096 + lr * 64 + lkx * 8;   // wm*64 rows
    const int boff = wn * 2048 + lr * 64 + lkx * 8;   // wn*32 rows

    STAGE128D(0);
    STAGE128D(1);
    asm volatile("s_waitcnt vmcnt(4)" ::: "memory");   // tile 0 landed (4/tile)
    __builtin_amdgcn_s_barrier();

    for (int t = 0; t < NT; ++t) {
        const bf16* Ab = (const bf16*)(smem + ((t & 1) << 14));
        const bf16* Bb = (const bf16*)(smem + 32768 + ((t & 1) << 14));
        short8 af[2][4], bv[2][2];
        #pragma unroll
        for (int kk = 0; kk < 2; kk++) {
            #pragma unroll
            for (int m = 0; m < 4; m++)
                af[kk][m] = *(const short8*)(Ab + aoff + m * 1024 + kk * 32);
            #pragma unroll
            for (int n = 0; n < 2; n++)
                bv[kk][n] = *(const short8*)(Bb + boff + n * 1024 + kk * 32);
        }
        asm volatile("s_waitcnt lgkmcnt(0)" ::: "memory");
        __builtin_amdgcn_sched_barrier(0);
        __builtin_amdgcn_s_barrier();          // all waves done reading buf[t&1]
        if (t + 2 < NT) STAGE128D(t + 2);      // overwrite buf[t&1] (now dead)
        __builtin_amdgcn_s_setprio(1);
        #pragma unroll
        for (int kk = 0; kk < 2; kk++)
            #pragma unroll
            for (int fm = 0; fm < 4; fm++)
                #pragma unroll
                for (int fn = 0; fn < 2; fn++)
                    acc[fm][fn] = __builtin_amdgcn_mfma_f32_16x16x32_bf16(
                        af[kk][fm], bv[kk][fn], acc[fm][fn], 0, 0, 0);
        __builtin_amdgcn_s_setprio(0);
        if (t + 2 < NT) {
            asm volatile("s_waitcnt vmcnt(4)" ::: "memory");   // tile t+1 landed
            __builtin_amdgcn_s_barrier();
        } else if (t + 1 < NT) {
            asm volatile("s_waitcnt vmcnt(0)" ::: "memory");   // final drain
            __builtin_amdgcn_s_barrier();
        }
    }
#undef STAGE128D

    #pragma unroll
    for (int fm = 0; fm < 4; fm++) {
        #pragma unroll
        for (int fn = 0; fn < 2; fn++) {
            const int col = bn * 128 + wn * 32 + fn * 16 + lr;
            #pragma unroll
            for (int r = 0; r < 4; r++) {
                const int row = bm * 128 + wm * 64 + fm * 16 + lk * 4 + r;
                float v = acc[fm][fn][r];
                if constexpr (EPI & 1) v += bias[col];
                if constexpr (EPI & 2) v = fmaxf(v, 0.f);
                if constexpr (EPI & 4) v += __bfloat162float(residB[(int64_t)row * N + col]);
                if constexpr (EPI & 8) outF[(int64_t)row * N + col] = v;
                else outB[(int64_t)row * N + col] = __float2bfloat16(v);
            }
        }
    }
}

// ---------------- MFMA flash attention v11: 3-deep LDS pipeline ----------
#if USE_PERMLANE
__device__ __forceinline__ float redmax16(float v) {
    uint32x2 s = __builtin_amdgcn_permlane16_swap(
        __float_as_uint(v), __float_as_uint(v), false, false);
    return fmaxf(__uint_as_float(s[0]), __uint_as_float(s[1]));
}
__device__ __forceinline__ float redmax32(float v) {
    uint32x2 s = __builtin_amdgcn_permlane32_swap(
        __float_as_uint(v), __float_as_uint(v), false, false);
    return fmaxf(__uint_as_float(s[0]), __uint_as_float(s[1]));
}
#endif

__device__ __forceinline__ void attn_tile(int k0, int qg, int nk,
        short8 qf0, short8 qf1,
        short8 kf00, short8 kf01, short8 kf10, short8 kf11,
        const short8 (&vf)[4], f32x4 (&ctx)[4], float& mrun, float& lrun,
        int c, int g, float scale2) {
    f32x4 st0 = {}, st1 = {};
    __builtin_amdgcn_s_setprio(1);
    st0 = __builtin_amdgcn_mfma_f32_16x16x32_bf16(kf00, qf0, st0, 0, 0, 0);
    st0 = __builtin_amdgcn_mfma_f32_16x16x32_bf16(kf01, qf1, st0, 0, 0, 0);
    const bool h2 = (k0 + 16 < nk);
    if (h2) {
        st1 = __builtin_amdgcn_mfma_f32_16x16x32_bf16(kf10, qf0, st1, 0, 0, 0);
        st1 = __builtin_amdgcn_mfma_f32_16x16x32_bf16(kf11, qf1, st1, 0, 0, 0);
    }
    __builtin_amdgcn_s_setprio(0);
    float sv[8];   // log2-domain scores
    #pragma unroll
    for (int r = 0; r < 4; r++) {
        int kg = k0 + 4 * g + r;
        sv[r] = (kg <= qg) ? st0[r] * scale2 : -INFINITY;
    }
    #pragma unroll
    for (int r = 0; r < 4; r++) {
        int kg = k0 + 16 + 4 * g + r;
        sv[4 + r] = (h2 && kg <= qg) ? st1[r] * scale2 : -INFINITY;
    }
    float bm = sv[0];
    #pragma unroll
    for (int i = 1; i < 8; i++) bm = fmaxf(bm, sv[i]);
#if USE_PERMLANE
    bm = redmax32(redmax16(bm));
#else
    bm = fmaxf(bm, __shfl_xor(bm, 16));
    bm = fmaxf(bm, __shfl_xor(bm, 32));
#endif
    if (__any(bm > mrun + 11.5416f)) {   // T13, log2 domain (= 8 nats)
        const float mnew = fmaxf(mrun, bm);
        const float facc = exp2f(mrun - mnew);   // 0 on first block
        lrun *= facc;
        #pragma unroll
        for (int dt = 0; dt < 4; dt++) ctx[dt] *= facc;
        mrun = mnew;
    }
    float p[8], psum = 0.f;
    #pragma unroll
    for (int i = 0; i < 8; i++) { p[i] = exp2f(sv[i] - mrun); psum += p[i]; }
    lrun += psum;                         // per-lane partial; reduced at epilogue

    auto pk = [](float a, float b2) -> uint32_t {
        uint16_t lo = __hip_bfloat16_raw(__float2bfloat16(a)).x;
        uint16_t hi = __hip_bfloat16_raw(__float2bfloat16(b2)).x;
        return (uint32_t)lo | ((uint32_t)hi << 16);
    };
    uint32_t w00 = pk(p[0], p[1]), w01 = pk(p[2], p[3]);   // tile0 keys 4g+{0..3}
    uint32_t w10 = pk(p[4], p[5]), w11 = pk(p[6], p[7]);   // tile1
    union { uint32_t u[4]; short8 v; } pa;
#if USE_PERMLANE
    uint32x2 sA = __builtin_amdgcn_permlane32_swap(w00, w10, false, false);
    uint32x2 sA2 = __builtin_amdgcn_permlane16_swap(sA[0], sA[1], false, false);
    uint32x2 sB = __builtin_amdgcn_permlane32_swap(w01, w11, false, false);
    uint32x2 sB2 = __builtin_amdgcn_permlane16_swap(sB[0], sB[1], false, false);
    pa.u[0] = sA2[0]; pa.u[2] = sA2[1];
    pa.u[1] = sB2[0]; pa.u[3] = sB2[1];
#else
    const int srcA = c + ((g & 1) << 5);
    const int srcB = srcA + 16;
    uint32_t x0 = (uint32_t)__shfl((int)w00, srcA);
    uint32_t x1 = (uint32_t)__shfl((int)w01, srcA);
    uint32_t x2 = (uint32_t)__shfl((int)w00, srcB);
    uint32_t x3 = (uint32_t)__shfl((int)w01, srcB);
    uint32_t y0 = (uint32_t)__shfl((int)w10, srcA);
    uint32_t y1 = (uint32_t)__shfl((int)w11, srcA);
    uint32_t y2 = (uint32_t)__shfl((int)w10, srcB);
    uint32_t y3 = (uint32_t)__shfl((int)w11, srcB);
    const bool hi2 = (g >= 2);
    pa.u[0] = hi2 ? y0 : x0; pa.u[1] = hi2 ? y1 : x1;
    pa.u[2] = hi2 ? y2 : x2; pa.u[3] = hi2 ? y3 : x3;
#endif

    __builtin_amdgcn_s_setprio(1);
    #pragma unroll
    for (int dt = 0; dt < 4; dt++)
        ctx[dt] = __builtin_amdgcn_mfma_f32_16x16x32_bf16(vf[dt], pa.v, ctx[dt], 0, 0, 0);
    __builtin_amdgcn_s_setprio(0);
}

__global__ __launch_bounds__(512) void k_attn6(const bf16* __restrict__ qkv,
        const bf16* __restrict__ Vt, bf16* __restrict__ O) {
    __shared__ __align__(16) bf16 kv[3][2][64 * 64];   // [buf][K|V][row][64], 48KB
    const int tid = threadIdx.x;
    const int lane = tid & 63;
    const int wave = tid >> 6;
    const int sbid = (blockIdx.x & 7) * 64 + (blockIdx.x >> 3);  // bijective on 512
    const int qp = ((sbid * 8) & 31) + wave;           // 8 consecutive pairs/block
    const int h = (sbid >> 2) & 15, b = sbid >> 6;
    const int q0A = qp * 16, q0B = (63 - qp) * 16;
    const int c = lane & 15, g = lane >> 4;
    const int qgA = q0A + c, qgB = q0B + c;
    const float scale2 = 1.4426950408889634f / 32.0f;  // log2e * D^-0.5

    const bf16* Qp = qkv;                  // cols 0..1023
    const bf16* qrowA = Qp + ((int64_t)(b * TT + q0A + c)) * QS + h * 64 + g * 8;
    short8 qA0 = *(const short8*)(qrowA);
    short8 qA1 = *(const short8*)(qrowA + 32);
    const bf16* qrowB = Qp + ((int64_t)(b * TT + q0B + c)) * QS + h * 64 + g * 8;
    short8 qB0 = *(const short8*)(qrowB);
    short8 qB1 = *(const short8*)(qrowB + 32);

    f32x4 ctxA[4] = {}, ctxB[4] = {};
    float mA = -INFINITY, lA = 0.f, mB = -INFINITY, lB = 0.f;

    const bf16* kg = qkv + 1024 + ((int64_t)b * TT) * QS + h * 64;  // K rows [t][64]
    const bf16* vg = Vt + ((int64_t)(b * TH + h) * 64) * TT;        // V rows [d][1024]

    const int nkA = q0A + 16, nkB = q0B + 16;
    const int nkMax = (63 - ((sbid * 8) & 31)) * 16 + 16;   // max over 8 waves

    // staging: thread owns LDS chunk (row0, s0); source chunk = s0 ^ (row0&7)
    const int row0 = tid >> 3, s0 = tid & 7, sx = (s0 ^ (row0 & 7)) * 8;

#define STAGEKV(bi, K0) do { \
        GLOAD16(kg + (int64_t)((K0) + row0) * QS + sx, &kv[bi][0][tid * 8]); \
        GLOAD16(vg + (int64_t)row0 * TT + (K0) + sx,   &kv[bi][1][tid * 8]); \
    } while (0)

    // swizzled LDS readers (row-major [64][64] bf16, chunk = 16B)
    auto kread = [&](int bi, int row, int ch) -> short8 {
        return *(const short8*)&kv[bi][0][row * 64 + ((ch ^ (row & 7)) * 8)];
    };
    auto vread = [&](int bi, int row, int ch) -> short8 {
        return *(const short8*)&kv[bi][1][row * 64 + ((ch ^ (row & 7)) * 8)];
    };

    STAGEKV(0, 0);
    if (64 < nkMax) STAGEKV(1, 64);

    int bi = 0;
    for (int k0 = 0; k0 < nkMax; k0 += 64) {
        // wait for buffer bi's loads (oldest 2): leave the younger stage in flight
        if (k0 + 64 < nkMax)
            asm volatile("s_waitcnt vmcnt(2)" ::: "memory");
        else
            asm volatile("s_waitcnt vmcnt(0)" ::: "memory");
        __syncthreads();            // all threads: bi loaded; bi-1 compute done
        const int bn2 = (bi + 2 >= 3) ? bi - 1 : bi + 2;
        if (k0 + 128 < nkMax) STAGEKV(bn2, k0 + 128);   // overwrites bi-1 (dead)
        #pragma unroll
        for (int sb2 = 0; sb2 < 2; sb2++) {         // two 32-key sub-blocks
            const int kl = sb2 * 32;                // local key base
            const int ks = k0 + kl;                 // global key base
            if (ks < nkB) {
                short8 kf00 = kread(bi, kl + c, g);
                short8 kf01 = kread(bi, kl + c, g + 4);
                short8 kf10 = kread(bi, kl + 16 + c, g);
                short8 kf11 = kread(bi, kl + 16 + c, g + 4);
                short8 vf[4];
                #pragma unroll
                for (int dt = 0; dt < 4; dt++)
                    vf[dt] = vread(bi, dt * 16 + c, (sb2 << 2) + g);
                attn_tile(ks, qgB, nkB, qB0, qB1, kf00, kf01, kf10, kf11, vf,
                          ctxB, mB, lB, c, g, scale2);
                if (ks < nkA)
                    attn_tile(ks, qgA, nkA, qA0, qA1, kf00, kf01, kf10, kf11, vf,
                              ctxA, mA, lA, c, g, scale2);
            }
        }
        bi = (bi + 1 == 3) ? 0 : bi + 1;
    }
#undef STAGEKV

    // reduce deferred per-lane l partials across g-groups (per query col c)
    lA += __shfl_xor(lA, 16); lA += __shfl_xor(lA, 32);
    lB += __shfl_xor(lB, 16); lB += __shfl_xor(lB, 32);

    const float invA = 1.0f / lA, invB = 1.0f / lB;
    bf16* orowA = O + ((int64_t)(b * TT + q0A + c)) * TD + h * 64 + g * 4;
    bf16* orowB = O + ((int64_t)(b * TT + q0B + c)) * TD + h * 64 + g * 4;
    #pragma unroll
    for (int dt = 0; dt < 4; dt++) {
        bf16 t4[4];
        #pragma unroll
        for (int r = 0; r < 4; r++) t4[r] = __float2bfloat16(ctxA[dt][r] * invA);
        *(uint2*)(orowA + dt * 16) = *(uint2*)t4;
        #pragma unroll
        for (int r = 0; r < 4; r++) t4[r] = __float2bfloat16(ctxB[dt][r] * invB);
        *(uint2*)(orowB + dt * 16) = *(uint2*)t4;
    }
}

extern "C" void kernel_launch(void* const* d_in, const int* in_sizes, int n_in,
                              void* d_out, int out_size, void* d_ws, size_t ws_size,
                              hipStream_t stream) {
    const int*   idx  = (const int*)  d_in[0];
    const float* tok  = (const float*)d_in[1];
    const float* pos  = (const float*)d_in[2];
    const float* wq   = (const float*)d_in[3];
    const float* wk   = (const float*)d_in[4];
    const float* wv   = (const float*)d_in[5];
    const float* wp   = (const float*)d_in[6];
    const float* bp   = (const float*)d_in[7];
    const float* ln1w = (const float*)d_in[8];
    const float* ln1b = (const float*)d_in[9];
    const float* ln2w = (const float*)d_in[10];
    const float* ln2b = (const float*)d_in[11];
    const float* w1   = (const float*)d_in[12];
    const float* b1   = (const float*)d_in[13];
    const float* w2   = (const float*)d_in[14];
    const float* b2   = (const float*)d_in[15];
    float* xout = (float*)d_out;   // final fp32 output

    char* ws = (char*)d_ws;
    size_t off = 0;
    auto alloc = [&](size_t bytes) {
        char* p = ws + off; off += (bytes + 255) & ~(size_t)255; return p;
    };
    bf16* xbf  = (bf16*)alloc((size_t)TM * TD * 2);   // bf16 residual stream
    bf16* h    = (bf16*)alloc((size_t)TM * TD * 2);
    bf16* qkv  = (bf16*)alloc((size_t)TM * QS * 2);
    bf16* ctx  = (bf16*)alloc((size_t)TM * TD * 2);
    bf16* ffa  = (bf16*)alloc((size_t)TM * TDF * 2);
    bf16* qkvT = (bf16*)alloc((size_t)TL * 3 * TD * TD * 2);
    bf16* wpT  = (bf16*)alloc((size_t)TL * TD * TD * 2);
    bf16* w1T  = (bf16*)alloc((size_t)TL * TD * TDF * 2);
    bf16* w2T  = (bf16*)alloc((size_t)TL * TD * TDF * 2);
    bf16* vt   = (bf16*)ffa;   // reuse: ffa is dead during attention

    // allow big dynamic LDS (idempotent)
    hipFuncSetAttribute((const void*)k_gemm256<16>,
        hipFuncAttributeMaxDynamicSharedMemorySize, 131072);
    hipFuncSetAttribute((const void*)k_gemm256<3>,
        hipFuncAttributeMaxDynamicSharedMemorySize, 131072);
    hipFuncSetAttribute((const void*)k_gemm128d<5>,
        hipFuncAttributeMaxDynamicSharedMemorySize, 65536);
    hipFuncSetAttribute((const void*)k_gemm128d<13>,
        hipFuncAttributeMaxDynamicSharedMemorySize, 65536);

    // all-layer weight transpose in one launch; tail overlaps k_embed
    k_wt<<<dim3(3072, TL), 256, 0, stream>>>(wq, wk, wv, wp, w1, w2,
                                             qkvT, wpT, w1T, w2T);
    k_embed<<<TM, 256, 0, stream>>>(idx, tok, pos, xbf);

    const int gQKV = (TM / 256) * (QS / 256);   // 384
    const int gF1  = (TM / 256) * (TDF / 256);  // 512
    const int gN1K = (TM / 128) * (TD / 128);   // 512 (proj & FFN2, 2 blocks/CU)

    for (int l = 0; l < TL; l++) {
        const bf16* qkvTl = qkvT + (int64_t)l * 3 * TD * TD;
        const bf16* wpTl  = wpT  + (int64_t)l * TD * TD;
        const bf16* w1Tl  = w1T  + (int64_t)l * TD * TDF;
        const bf16* w2Tl  = w2T  + (int64_t)l * TDF * TD;

        k_ln<<<TM, 256, 0, stream>>>(xbf, ln1w + l * TD, ln1b + l * TD, h);
        k_gemm256<16><<<gQKV, 512, 131072, stream>>>(h, qkvTl, nullptr, nullptr, qkv, vt, TM, QS, TD);
        k_attn6<<<512, 512, 0, stream>>>(qkv, vt, ctx);
        k_gemm128d<5><<<gN1K, 512, 65536, stream>>>(ctx, wpTl, bp + l * TD, xbf, nullptr, xbf, TM, TD, TD);
        k_ln<<<TM, 256, 0, stream>>>(xbf, ln2w + l * TD, ln2b + l * TD, h);
        k_gemm256<3><<<gF1, 512, 131072, stream>>>(h, w1Tl, b1 + l * TDF, nullptr, ffa, nullptr, TM, TDF, TD);
        if (l + 1 < TL)
            k_gemm128d<5><<<gN1K, 512, 65536, stream>>>(ffa, w2Tl, b2 + l * TD, xbf, nullptr, xbf, TM, TD, TDF);
        else
            k_gemm128d<13><<<gN1K, 512, 65536, stream>>>(ffa, w2Tl, b2 + l * TD, xbf, xout, nullptr, TM, TD, TDF);
    }
    (void)in_sizes; (void)n_in; (void)out_size; (void)ws_size;
}

// Round 20
// 1320.384 us; speedup vs baseline: 1.0540x; 1.0540x over previous
//
#include <hip/hip_runtime.h>
#include <hip/hip_bf16.h>
#include <stdint.h>

typedef __hip_bfloat16 bf16;
typedef __attribute__((ext_vector_type(8))) short short8;
typedef __attribute__((ext_vector_type(4))) float f32x4;
typedef __attribute__((ext_vector_type(2))) unsigned int uint32x2;

static constexpr int TB = 8;     // batch
static constexpr int TT = 1024;  // seq len
static constexpr int TD = 1024;  // d_model
static constexpr int TH = 16;    // heads
static constexpr int TL = 4;     // layers
static constexpr int TDF = 4096; // ffn dim
static constexpr int TM = TB * TT; // 8192 rows
static constexpr int QS = 3072;  // fused qkv row stride

#if __has_builtin(__builtin_amdgcn_permlane16_swap) && __has_builtin(__builtin_amdgcn_permlane32_swap)
#define USE_PERMLANE 1
#else
#define USE_PERMLANE 0
#endif

#define GLOAD16(g, l) __builtin_amdgcn_global_load_lds( \
    (const __attribute__((address_space(1))) unsigned int*)(g), \
    (__attribute__((address_space(3))) unsigned int*)(l), 16, 0, 0)

// ------------- embedding: xbf = bf16(tok_emb[idx] + pos_emb) -------------
__global__ __launch_bounds__(256) void k_embed(const int* __restrict__ idx,
        const float* __restrict__ tok, const float* __restrict__ pos,
        bf16* __restrict__ xbf) {
    int row = blockIdx.x;            // b*T + t
    int t = row & (TT - 1);
    int token = idx[row];
    int c = threadIdx.x * 4;
    float4 tv = *(const float4*)(tok + (int64_t)token * TD + c);
    float4 pv = *(const float4*)(pos + (int64_t)t * TD + c);
    bf16 t4[4];
    t4[0] = __float2bfloat16(tv.x + pv.x);
    t4[1] = __float2bfloat16(tv.y + pv.y);
    t4[2] = __float2bfloat16(tv.z + pv.z);
    t4[3] = __float2bfloat16(tv.w + pv.w);
    *(uint2*)(xbf + (int64_t)row * TD + c) = *(uint2*)t4;
}

// ---------------- layernorm: bf16 in -> bf16 out ----------------
__global__ __launch_bounds__(256) void k_ln(const bf16* __restrict__ x,
        const float* __restrict__ w, const float* __restrict__ b,
        bf16* __restrict__ out) {
    int row = blockIdx.x;
    int tid = threadIdx.x;
    const bf16* xr = x + (int64_t)row * TD;
    uint2 raw = *(const uint2*)(xr + tid * 4);
    const bf16* rp = (const bf16*)&raw;
    float v0 = __bfloat162float(rp[0]), v1 = __bfloat162float(rp[1]);
    float v2 = __bfloat162float(rp[2]), v3 = __bfloat162float(rp[3]);
    float s  = v0 + v1 + v2 + v3;
    float s2 = v0*v0 + v1*v1 + v2*v2 + v3*v3;
    #pragma unroll
    for (int off = 32; off; off >>= 1) { s += __shfl_xor(s, off); s2 += __shfl_xor(s2, off); }
    __shared__ float red[8];
    int wv_ = tid >> 6, ln_ = tid & 63;
    if (ln_ == 0) { red[wv_] = s; red[4 + wv_] = s2; }
    __syncthreads();
    s  = red[0] + red[1] + red[2] + red[3];
    s2 = red[4] + red[5] + red[6] + red[7];
    float mean = s * (1.f / TD);
    float var  = s2 * (1.f / TD) - mean * mean;
    float rstd = rsqrtf(var + 1e-5f);
    float4 wv4 = *(const float4*)(w + tid * 4);
    float4 bv4 = *(const float4*)(b + tid * 4);
    bf16 t4[4];
    t4[0] = __float2bfloat16((v0 - mean) * rstd * wv4.x + bv4.x);
    t4[1] = __float2bfloat16((v1 - mean) * rstd * wv4.y + bv4.y);
    t4[2] = __float2bfloat16((v2 - mean) * rstd * wv4.z + bv4.z);
    t4[3] = __float2bfloat16((v3 - mean) * rstd * wv4.w + bv4.w);
    *(uint2*)(out + (int64_t)row * TD + tid * 4) = *(uint2*)t4;
}

// ------------- fused weight transpose+cvt for one layer (1 launch) ---------
// Per-layer (not batched): freshly transposed weights stay L2/L3-warm for the
// immediately following GEMMs (r19 showed all-layer batching costs ~70 us).
__global__ __launch_bounds__(256) void k_wt(
        const float* __restrict__ wq, const float* __restrict__ wk,
        const float* __restrict__ wv, const float* __restrict__ wp,
        const float* __restrict__ w1, const float* __restrict__ w2,
        bf16* __restrict__ qkvT, bf16* __restrict__ wpT,
        bf16* __restrict__ w1T, bf16* __restrict__ w2T) {
    __shared__ bf16 tile[64 * 74];
    const int id = blockIdx.x;
    const float* src; bf16* dst; int K, N, n0, k0;
    if (id < 768) {
        int w = id >> 8, r = id & 255;
        src = (w == 0) ? wq : ((w == 1) ? wk : wv);
        dst = qkvT + (int64_t)w * 1024 * 1024;
        K = 1024; N = 1024; n0 = (r & 15) * 64; k0 = (r >> 4) * 64;
    } else if (id < 1024) {
        int r = id - 768; src = wp; dst = wpT;
        K = 1024; N = 1024; n0 = (r & 15) * 64; k0 = (r >> 4) * 64;
    } else if (id < 2048) {
        int r = id - 1024; src = w1; dst = w1T;
        K = 1024; N = 4096; n0 = (r & 63) * 64; k0 = (r >> 6) * 64;
    } else {
        int r = id - 2048; src = w2; dst = w2T;
        K = 4096; N = 1024; n0 = (r & 15) * 64; k0 = (r >> 4) * 64;
    }
    const int tid = threadIdx.x;
    #pragma unroll
    for (int i = 0; i < 16; i++) {
        int q = i * 256 + tid;
        int r = q >> 6, c = q & 63;
        tile[r * 74 + c] = __float2bfloat16(src[(int64_t)(k0 + r) * N + n0 + c]);
    }
    __syncthreads();
    #pragma unroll
    for (int i = 0; i < 16; i++) {
        int q = i * 256 + tid;
        int nr = q >> 6, kc = q & 63;
        dst[(int64_t)(n0 + nr) * K + k0 + kc] = tile[kc * 74 + nr];
    }
}

// ------------- GEMM 256x256 deep-pipelined (T2+T3+T4+T5) -------------
// EPI bits: 1=+bias, 2=relu, 8=fp32 out, 16=QKV mode (V cols >=2048 written
// transposed to vtp as [b][h][64 dims][1024 tokens]).
template<int EPI>
__global__ __launch_bounds__(512, 2) void k_gemm256(const bf16* __restrict__ A,
        const bf16* __restrict__ BT, const float* __restrict__ bias,
        float* __restrict__ outF, bf16* __restrict__ outB,
        bf16* __restrict__ vtp, int M, int N, int K) {
    extern __shared__ __align__(16) char smem[];   // [A0|A1|B0|B1] 32KB each
    const int tid = threadIdx.x;
    const int lane = tid & 63, wave = tid >> 6;
    const int wm = wave >> 2, wn = wave & 3;       // per-wave out: 128x64
    const int lr = lane & 15, lk = lane >> 4;
    const int nb = gridDim.x;                      // % 8 == 0
    const int sb = (blockIdx.x & 7) * (nb >> 3) + (blockIdx.x >> 3);
    const int nbn = N >> 8;
    const int bm = sb / nbn, bn = sb % nbn;
    const int64_t aBase = (int64_t)bm * 256 * K;
    const int64_t bBase = (int64_t)bn * 256 * K;
    const int NT = K >> 6;

    const int tswz = tid ^ (((tid >> 5) & 1) << 1);
    const int row0 = tswz >> 3, s0 = tswz & 7;

#define STAGE256(tt) do { \
        char* Ad_ = smem + (((tt) & 1) << 15); \
        char* Bd_ = smem + 65536 + (((tt) & 1) << 15); \
        _Pragma("unroll") \
        for (int j = 0; j < 4; j++) { \
            const int rr_ = j * 64 + row0; \
            GLOAD16(A  + aBase + (int64_t)rr_ * K + (tt) * 64 + s0 * 8, Ad_ + (j * 512 + tid) * 16); \
            GLOAD16(BT + bBase + (int64_t)rr_ * K + (tt) * 64 + s0 * 8, Bd_ + (j * 512 + tid) * 16); \
        } \
    } while (0)

    f32x4 acc[8][4] = {};
    const int lkx = lk ^ ((lr & 4) >> 1);          // read-side st swizzle
    const int aoff = wm * 8192 + lr * 64 + lkx * 8;
    const int boff = wn * 4096 + lr * 64 + lkx * 8;

    STAGE256(0);
    STAGE256(1);
    asm volatile("s_waitcnt vmcnt(8)" ::: "memory");   // tile 0 landed
    __builtin_amdgcn_s_barrier();

    for (int t = 0; t < NT; ++t) {
        const bf16* Ab = (const bf16*)(smem + ((t & 1) << 15));
        const bf16* Bb = (const bf16*)(smem + 65536 + ((t & 1) << 15));
        short8 af[2][8], bv[2][4];
        #pragma unroll
        for (int kk = 0; kk < 2; kk++) {
            #pragma unroll
            for (int m = 0; m < 8; m++)
                af[kk][m] = *(const short8*)(Ab + aoff + m * 1024 + kk * 32);
            #pragma unroll
            for (int n = 0; n < 4; n++)
                bv[kk][n] = *(const short8*)(Bb + boff + n * 1024 + kk * 32);
        }
        asm volatile("s_waitcnt lgkmcnt(0)" ::: "memory");
        __builtin_amdgcn_sched_barrier(0);
        __builtin_amdgcn_s_barrier();          // all waves done reading buf[t&1]
        if (t + 2 < NT) STAGE256(t + 2);       // overwrite buf[t&1] (now dead)
        __builtin_amdgcn_s_setprio(1);
        #pragma unroll
        for (int kk = 0; kk < 2; kk++)
            #pragma unroll
            for (int fm = 0; fm < 8; fm++)
                #pragma unroll
                for (int fn = 0; fn < 4; fn++)
                    acc[fm][fn] = __builtin_amdgcn_mfma_f32_16x16x32_bf16(
                        af[kk][fm], bv[kk][fn], acc[fm][fn], 0, 0, 0);
        __builtin_amdgcn_s_setprio(0);
        if (t + 2 < NT) {
            asm volatile("s_waitcnt vmcnt(8)" ::: "memory");   // tile t+1 landed
            __builtin_amdgcn_s_barrier();
        } else if (t + 1 < NT) {
            asm volatile("s_waitcnt vmcnt(0)" ::: "memory");   // final drain
            __builtin_amdgcn_s_barrier();
        }
    }
#undef STAGE256

    #pragma unroll
    for (int fm = 0; fm < 8; fm++) {
        #pragma unroll
        for (int fn = 0; fn < 4; fn++) {
            const int col = bn * 256 + wn * 64 + fn * 16 + lr;
            if constexpr (EPI & 16) {
                const int trow = bm * 256 + wm * 128 + fm * 16 + lk * 4;
                if (col >= 2048) {
                    // V column: write transposed vt[b][h][d][t], 4 tokens = 8B
                    const int d = col - 2048;
                    bf16 t4[4];
                    #pragma unroll
                    for (int r = 0; r < 4; r++)
                        t4[r] = __float2bfloat16(acc[fm][fn][r]);
                    const int bb = trow >> 10, tt2 = trow & 1023;
                    *(uint2*)(vtp + ((int64_t)((bb * TH + (d >> 6)) * 64 + (d & 63)) * TT + tt2)) = *(uint2*)t4;
                } else {
                    #pragma unroll
                    for (int r = 0; r < 4; r++)
                        outB[(int64_t)(trow + r) * N + col] = __float2bfloat16(acc[fm][fn][r]);
                }
            } else {
                #pragma unroll
                for (int r = 0; r < 4; r++) {
                    const int row = bm * 256 + wm * 128 + fm * 16 + lk * 4 + r;
                    float v = acc[fm][fn][r];
                    if constexpr (EPI & 1) v += bias[col];
                    if constexpr (EPI & 2) v = fmaxf(v, 0.f);
                    if constexpr (EPI & 8) outF[(int64_t)row * N + col] = v;
                    else outB[(int64_t)row * N + col] = __float2bfloat16(v);
                }
            }
        }
    }
}

// ------------- GEMM 128x128 deep-pipelined (64KB LDS, 2 blocks/CU) -------
// EPI bits: 1=+bias, 2=relu, 4=+bf16 residual, 8=fp32 out (else bf16 out)
template<int EPI>
__global__ __launch_bounds__(512, 2) void k_gemm128d(const bf16* __restrict__ A,
        const bf16* __restrict__ BT, const float* __restrict__ bias,
        const bf16* __restrict__ residB,
        float* __restrict__ outF, bf16* __restrict__ outB, int M, int N, int K) {
    extern __shared__ __align__(16) char smem[];   // A0|A1|B0|B1 = 16KB each
    const int tid = threadIdx.x;
    const int lane = tid & 63, wave = tid >> 6;
    const int wm = wave >> 2, wn = wave & 3;       // 2Mx4N, per-wave 64x32
    const int lr = lane & 15, lk = lane >> 4;
    const int nb = gridDim.x;                      // % 8 == 0
    const int sb = (blockIdx.x & 7) * (nb >> 3) + (blockIdx.x >> 3);
    const int nbn = N >> 7;
    const int bm = sb / nbn, bn = sb % nbn;
    const int64_t aBase = (int64_t)bm * 128 * K;
    const int64_t bBase = (int64_t)bn * 128 * K;
    const int NT = K >> 6;

    const int tswz = tid ^ (((tid >> 5) & 1) << 1);
    const int row0 = tswz >> 3, s0 = tswz & 7;     // rows 0..63, chunk 0..7

#define STAGE128D(tt) do { \
        char* Ad_ = smem + (((tt) & 1) << 14); \
        char* Bd_ = smem + 32768 + (((tt) & 1) << 14); \
        _Pragma("unroll") \
        for (int j = 0; j < 2; j++) { \
            const int rr_ = j * 64 + row0; \
            GLOAD16(A  + aBase + (int64_t)rr_ * K + (tt) * 64 + s0 * 8, Ad_ + (j * 512 + tid) * 16); \
            GLOAD16(BT + bBase + (int64_t)rr_ * K + (tt) * 64 + s0 * 8, Bd_ + (j * 512 + tid) * 16); \
        } \
    } while (0)

    f32x4 acc[4][2] = {};
    const int lkx = lk ^ ((lr & 4) >> 1);          // read-side st swizzle
    const int aoff = wm * 4096 + lr * 64 + lkx * 8;   // wm*64 rows
    const int boff = wn * 2048 + lr * 64 + lkx * 8;   // wn*32 rows

    STAGE128D(0);
    STAGE128D(1);
    asm volatile("s_waitcnt vmcnt(4)" ::: "memory");   // tile 0 landed (4/tile)
    __builtin_amdgcn_s_barrier();

    for (int t = 0; t < NT; ++t) {
        const bf16* Ab = (const bf16*)(smem + ((t & 1) << 14));
        const bf16* Bb = (const bf16*)(smem + 32768 + ((t & 1) << 14));
        short8 af[2][4], bv[2][2];
        #pragma unroll
        for (int kk = 0; kk < 2; kk++) {
            #pragma unroll
            for (int m = 0; m < 4; m++)
                af[kk][m] = *(const short8*)(Ab + aoff + m * 1024 + kk * 32);
            #pragma unroll
            for (int n = 0; n < 2; n++)
                bv[kk][n] = *(const short8*)(Bb + boff + n * 1024 + kk * 32);
        }
        asm volatile("s_waitcnt lgkmcnt(0)" ::: "memory");
        __builtin_amdgcn_sched_barrier(0);
        __builtin_amdgcn_s_barrier();          // all waves done reading buf[t&1]
        if (t + 2 < NT) STAGE128D(t + 2);      // overwrite buf[t&1] (now dead)
        __builtin_amdgcn_s_setprio(1);
        #pragma unroll
        for (int kk = 0; kk < 2; kk++)
            #pragma unroll
            for (int fm = 0; fm < 4; fm++)
                #pragma unroll
                for (int fn = 0; fn < 2; fn++)
                    acc[fm][fn] = __builtin_amdgcn_mfma_f32_16x16x32_bf16(
                        af[kk][fm], bv[kk][fn], acc[fm][fn], 0, 0, 0);
        __builtin_amdgcn_s_setprio(0);
        if (t + 2 < NT) {
            asm volatile("s_waitcnt vmcnt(4)" ::: "memory");   // tile t+1 landed
            __builtin_amdgcn_s_barrier();
        } else if (t + 1 < NT) {
            asm volatile("s_waitcnt vmcnt(0)" ::: "memory");   // final drain
            __builtin_amdgcn_s_barrier();
        }
    }
#undef STAGE128D

    #pragma unroll
    for (int fm = 0; fm < 4; fm++) {
        #pragma unroll
        for (int fn = 0; fn < 2; fn++) {
            const int col = bn * 128 + wn * 32 + fn * 16 + lr;
            #pragma unroll
            for (int r = 0; r < 4; r++) {
                const int row = bm * 128 + wm * 64 + fm * 16 + lk * 4 + r;
                float v = acc[fm][fn][r];
                if constexpr (EPI & 1) v += bias[col];
                if constexpr (EPI & 2) v = fmaxf(v, 0.f);
                if constexpr (EPI & 4) v += __bfloat162float(residB[(int64_t)row * N + col]);
                if constexpr (EPI & 8) outF[(int64_t)row * N + col] = v;
                else outB[(int64_t)row * N + col] = __float2bfloat16(v);
            }
        }
    }
}

// ---------------- MFMA flash attention v11: 3-deep LDS pipeline ----------
#if USE_PERMLANE
__device__ __forceinline__ float redmax16(float v) {
    uint32x2 s = __builtin_amdgcn_permlane16_swap(
        __float_as_uint(v), __float_as_uint(v), false, false);
    return fmaxf(__uint_as_float(s[0]), __uint_as_float(s[1]));
}
__device__ __forceinline__ float redmax32(float v) {
    uint32x2 s = __builtin_amdgcn_permlane32_swap(
        __float_as_uint(v), __float_as_uint(v), false, false);
    return fmaxf(__uint_as_float(s[0]), __uint_as_float(s[1]));
}
#endif

__device__ __forceinline__ void attn_tile(int k0, int qg, int nk,
        short8 qf0, short8 qf1,
        short8 kf00, short8 kf01, short8 kf10, short8 kf11,
        const short8 (&vf)[4], f32x4 (&ctx)[4], float& mrun, float& lrun,
        int c, int g, float scale2) {
    f32x4 st0 = {}, st1 = {};
    __builtin_amdgcn_s_setprio(1);
    st0 = __builtin_amdgcn_mfma_f32_16x16x32_bf16(kf00, qf0, st0, 0, 0, 0);
    st0 = __builtin_amdgcn_mfma_f32_16x16x32_bf16(kf01, qf1, st0, 0, 0, 0);
    const bool h2 = (k0 + 16 < nk);
    if (h2) {
        st1 = __builtin_amdgcn_mfma_f32_16x16x32_bf16(kf10, qf0, st1, 0, 0, 0);
        st1 = __builtin_amdgcn_mfma_f32_16x16x32_bf16(kf11, qf1, st1, 0, 0, 0);
    }
    __builtin_amdgcn_s_setprio(0);
    float sv[8];   // log2-domain scores
    #pragma unroll
    for (int r = 0; r < 4; r++) {
        int kg = k0 + 4 * g + r;
        sv[r] = (kg <= qg) ? st0[r] * scale2 : -INFINITY;
    }
    #pragma unroll
    for (int r = 0; r < 4; r++) {
        int kg = k0 + 16 + 4 * g + r;
        sv[4 + r] = (h2 && kg <= qg) ? st1[r] * scale2 : -INFINITY;
    }
    float bm = sv[0];
    #pragma unroll
    for (int i = 1; i < 8; i++) bm = fmaxf(bm, sv[i]);
#if USE_PERMLANE
    bm = redmax32(redmax16(bm));
#else
    bm = fmaxf(bm, __shfl_xor(bm, 16));
    bm = fmaxf(bm, __shfl_xor(bm, 32));
#endif
    if (__any(bm > mrun + 11.5416f)) {   // T13, log2 domain (= 8 nats)
        const float mnew = fmaxf(mrun, bm);
        const float facc = exp2f(mrun - mnew);   // 0 on first block
        lrun *= facc;
        #pragma unroll
        for (int dt = 0; dt < 4; dt++) ctx[dt] *= facc;
        mrun = mnew;
    }
    float p[8], psum = 0.f;
    #pragma unroll
    for (int i = 0; i < 8; i++) { p[i] = exp2f(sv[i] - mrun); psum += p[i]; }
    lrun += psum;                         // per-lane partial; reduced at epilogue

    auto pk = [](float a, float b2) -> uint32_t {
        uint16_t lo = __hip_bfloat16_raw(__float2bfloat16(a)).x;
        uint16_t hi = __hip_bfloat16_raw(__float2bfloat16(b2)).x;
        return (uint32_t)lo | ((uint32_t)hi << 16);
    };
    uint32_t w00 = pk(p[0], p[1]), w01 = pk(p[2], p[3]);   // tile0 keys 4g+{0..3}
    uint32_t w10 = pk(p[4], p[5]), w11 = pk(p[6], p[7]);   // tile1
    union { uint32_t u[4]; short8 v; } pa;
#if USE_PERMLANE
    uint32x2 sA = __builtin_amdgcn_permlane32_swap(w00, w10, false, false);
    uint32x2 sA2 = __builtin_amdgcn_permlane16_swap(sA[0], sA[1], false, false);
    uint32x2 sB = __builtin_amdgcn_permlane32_swap(w01, w11, false, false);
    uint32x2 sB2 = __builtin_amdgcn_permlane16_swap(sB[0], sB[1], false, false);
    pa.u[0] = sA2[0]; pa.u[2] = sA2[1];
    pa.u[1] = sB2[0]; pa.u[3] = sB2[1];
#else
    const int srcA = c + ((g & 1) << 5);
    const int srcB = srcA + 16;
    uint32_t x0 = (uint32_t)__shfl((int)w00, srcA);
    uint32_t x1 = (uint32_t)__shfl((int)w01, srcA);
    uint32_t x2 = (uint32_t)__shfl((int)w00, srcB);
    uint32_t x3 = (uint32_t)__shfl((int)w01, srcB);
    uint32_t y0 = (uint32_t)__shfl((int)w10, srcA);
    uint32_t y1 = (uint32_t)__shfl((int)w11, srcA);
    uint32_t y2 = (uint32_t)__shfl((int)w10, srcB);
    uint32_t y3 = (uint32_t)__shfl((int)w11, srcB);
    const bool hi2 = (g >= 2);
    pa.u[0] = hi2 ? y0 : x0; pa.u[1] = hi2 ? y1 : x1;
    pa.u[2] = hi2 ? y2 : x2; pa.u[3] = hi2 ? y3 : x3;
#endif

    __builtin_amdgcn_s_setprio(1);
    #pragma unroll
    for (int dt = 0; dt < 4; dt++)
        ctx[dt] = __builtin_amdgcn_mfma_f32_16x16x32_bf16(vf[dt], pa.v, ctx[dt], 0, 0, 0);
    __builtin_amdgcn_s_setprio(0);
}

__global__ __launch_bounds__(512) void k_attn6(const bf16* __restrict__ qkv,
        const bf16* __restrict__ Vt, bf16* __restrict__ O) {
    __shared__ __align__(16) bf16 kv[3][2][64 * 64];   // [buf][K|V][row][64], 48KB
    const int tid = threadIdx.x;
    const int lane = tid & 63;
    const int wave = tid >> 6;
    const int sbid = (blockIdx.x & 7) * 64 + (blockIdx.x >> 3);  // bijective on 512
    const int qp = ((sbid * 8) & 31) + wave;           // 8 consecutive pairs/block
    const int h = (sbid >> 2) & 15, b = sbid >> 6;
    const int q0A = qp * 16, q0B = (63 - qp) * 16;
    const int c = lane & 15, g = lane >> 4;
    const int qgA = q0A + c, qgB = q0B + c;
    const float scale2 = 1.4426950408889634f / 32.0f;  // log2e * D^-0.5

    const bf16* Qp = qkv;                  // cols 0..1023
    const bf16* qrowA = Qp + ((int64_t)(b * TT + q0A + c)) * QS + h * 64 + g * 8;
    short8 qA0 = *(const short8*)(qrowA);
    short8 qA1 = *(const short8*)(qrowA + 32);
    const bf16* qrowB = Qp + ((int64_t)(b * TT + q0B + c)) * QS + h * 64 + g * 8;
    short8 qB0 = *(const short8*)(qrowB);
    short8 qB1 = *(const short8*)(qrowB + 32);

    f32x4 ctxA[4] = {}, ctxB[4] = {};
    float mA = -INFINITY, lA = 0.f, mB = -INFINITY, lB = 0.f;

    const bf16* kg = qkv + 1024 + ((int64_t)b * TT) * QS + h * 64;  // K rows [t][64]
    const bf16* vg = Vt + ((int64_t)(b * TH + h) * 64) * TT;        // V rows [d][1024]

    const int nkA = q0A + 16, nkB = q0B + 16;
    const int nkMax = (63 - ((sbid * 8) & 31)) * 16 + 16;   // max over 8 waves

    // staging: thread owns LDS chunk (row0, s0); source chunk = s0 ^ (row0&7)
    const int row0 = tid >> 3, s0 = tid & 7, sx = (s0 ^ (row0 & 7)) * 8;

#define STAGEKV(bi, K0) do { \
        GLOAD16(kg + (int64_t)((K0) + row0) * QS + sx, &kv[bi][0][tid * 8]); \
        GLOAD16(vg + (int64_t)row0 * TT + (K0) + sx,   &kv[bi][1][tid * 8]); \
    } while (0)

    // swizzled LDS readers (row-major [64][64] bf16, chunk = 16B)
    auto kread = [&](int bi, int row, int ch) -> short8 {
        return *(const short8*)&kv[bi][0][row * 64 + ((ch ^ (row & 7)) * 8)];
    };
    auto vread = [&](int bi, int row, int ch) -> short8 {
        return *(const short8*)&kv[bi][1][row * 64 + ((ch ^ (row & 7)) * 8)];
    };

    STAGEKV(0, 0);
    if (64 < nkMax) STAGEKV(1, 64);

    int bi = 0;
    for (int k0 = 0; k0 < nkMax; k0 += 64) {
        // wait for buffer bi's loads (oldest 2): leave the younger stage in flight
        if (k0 + 64 < nkMax)
            asm volatile("s_waitcnt vmcnt(2)" ::: "memory");
        else
            asm volatile("s_waitcnt vmcnt(0)" ::: "memory");
        __syncthreads();            // all threads: bi loaded; bi-1 compute done
        const int bn2 = (bi + 2 >= 3) ? bi - 1 : bi + 2;
        if (k0 + 128 < nkMax) STAGEKV(bn2, k0 + 128);   // overwrites bi-1 (dead)
        #pragma unroll
        for (int sb2 = 0; sb2 < 2; sb2++) {         // two 32-key sub-blocks
            const int kl = sb2 * 32;                // local key base
            const int ks = k0 + kl;                 // global key base
            if (ks < nkB) {
                short8 kf00 = kread(bi, kl + c, g);
                short8 kf01 = kread(bi, kl + c, g + 4);
                short8 kf10 = kread(bi, kl + 16 + c, g);
                short8 kf11 = kread(bi, kl + 16 + c, g + 4);
                short8 vf[4];
                #pragma unroll
                for (int dt = 0; dt < 4; dt++)
                    vf[dt] = vread(bi, dt * 16 + c, (sb2 << 2) + g);
                attn_tile(ks, qgB, nkB, qB0, qB1, kf00, kf01, kf10, kf11, vf,
                          ctxB, mB, lB, c, g, scale2);
                if (ks < nkA)
                    attn_tile(ks, qgA, nkA, qA0, qA1, kf00, kf01, kf10, kf11, vf,
                              ctxA, mA, lA, c, g, scale2);
            }
        }
        bi = (bi + 1 == 3) ? 0 : bi + 1;
    }
#undef STAGEKV

    // reduce deferred per-lane l partials across g-groups (per query col c)
    lA += __shfl_xor(lA, 16); lA += __shfl_xor(lA, 32);
    lB += __shfl_xor(lB, 16); lB += __shfl_xor(lB, 32);

    const float invA = 1.0f / lA, invB = 1.0f / lB;
    bf16* orowA = O + ((int64_t)(b * TT + q0A + c)) * TD + h * 64 + g * 4;
    bf16* orowB = O + ((int64_t)(b * TT + q0B + c)) * TD + h * 64 + g * 4;
    #pragma unroll
    for (int dt = 0; dt < 4; dt++) {
        bf16 t4[4];
        #pragma unroll
        for (int r = 0; r < 4; r++) t4[r] = __float2bfloat16(ctxA[dt][r] * invA);
        *(uint2*)(orowA + dt * 16) = *(uint2*)t4;
        #pragma unroll
        for (int r = 0; r < 4; r++) t4[r] = __float2bfloat16(ctxB[dt][r] * invB);
        *(uint2*)(orowB + dt * 16) = *(uint2*)t4;
    }
}

extern "C" void kernel_launch(void* const* d_in, const int* in_sizes, int n_in,
                              void* d_out, int out_size, void* d_ws, size_t ws_size,
                              hipStream_t stream) {
    const int*   idx  = (const int*)  d_in[0];
    const float* tok  = (const float*)d_in[1];
    const float* pos  = (const float*)d_in[2];
    const float* wq   = (const float*)d_in[3];
    const float* wk   = (const float*)d_in[4];
    const float* wv   = (const float*)d_in[5];
    const float* wp   = (const float*)d_in[6];
    const float* bp   = (const float*)d_in[7];
    const float* ln1w = (const float*)d_in[8];
    const float* ln1b = (const float*)d_in[9];
    const float* ln2w = (const float*)d_in[10];
    const float* ln2b = (const float*)d_in[11];
    const float* w1   = (const float*)d_in[12];
    const float* b1   = (const float*)d_in[13];
    const float* w2   = (const float*)d_in[14];
    const float* b2   = (const float*)d_in[15];
    float* xout = (float*)d_out;   // final fp32 output

    char* ws = (char*)d_ws;
    size_t off = 0;
    auto alloc = [&](size_t bytes) {
        char* p = ws + off; off += (bytes + 255) & ~(size_t)255; return p;
    };
    bf16* xbf  = (bf16*)alloc((size_t)TM * TD * 2);   // bf16 residual stream
    bf16* h    = (bf16*)alloc((size_t)TM * TD * 2);
    bf16* qkv  = (bf16*)alloc((size_t)TM * QS * 2);
    bf16* ctx  = (bf16*)alloc((size_t)TM * TD * 2);
    bf16* ffa  = (bf16*)alloc((size_t)TM * TDF * 2);
    bf16* qkvT = (bf16*)alloc((size_t)3 * TD * TD * 2);
    bf16* wpT  = (bf16*)alloc((size_t)TD * TD * 2);
    bf16* w1T  = (bf16*)alloc((size_t)TD * TDF * 2);
    bf16* w2T  = (bf16*)alloc((size_t)TD * TDF * 2);
    bf16* vt   = (bf16*)ffa;   // reuse: ffa is dead during attention

    // allow big dynamic LDS (idempotent)
    hipFuncSetAttribute((const void*)k_gemm256<16>,
        hipFuncAttributeMaxDynamicSharedMemorySize, 131072);
    hipFuncSetAttribute((const void*)k_gemm256<3>,
        hipFuncAttributeMaxDynamicSharedMemorySize, 131072);
    hipFuncSetAttribute((const void*)k_gemm128d<5>,
        hipFuncAttributeMaxDynamicSharedMemorySize, 65536);
    hipFuncSetAttribute((const void*)k_gemm128d<13>,
        hipFuncAttributeMaxDynamicSharedMemorySize, 65536);

    k_embed<<<TM, 256, 0, stream>>>(idx, tok, pos, xbf);

    const int gQKV = (TM / 256) * (QS / 256);   // 384
    const int gF1  = (TM / 256) * (TDF / 256);  // 512
    const int gN1K = (TM / 128) * (TD / 128);   // 512 (proj & FFN2, 2 blocks/CU)

    for (int l = 0; l < TL; l++) {
        k_wt<<<3072, 256, 0, stream>>>(
            wq + (int64_t)l * TD * TD, wk + (int64_t)l * TD * TD,
            wv + (int64_t)l * TD * TD, wp + (int64_t)l * TD * TD,
            w1 + (int64_t)l * TD * TDF, w2 + (int64_t)l * TDF * TD,
            qkvT, wpT, w1T, w2T);

        k_ln<<<TM, 256, 0, stream>>>(xbf, ln1w + l * TD, ln1b + l * TD, h);
        k_gemm256<16><<<gQKV, 512, 131072, stream>>>(h, qkvT, nullptr, nullptr, qkv, vt, TM, QS, TD);
        k_attn6<<<512, 512, 0, stream>>>(qkv, vt, ctx);
        k_gemm128d<5><<<gN1K, 512, 65536, stream>>>(ctx, wpT, bp + l * TD, xbf, nullptr, xbf, TM, TD, TD);
        k_ln<<<TM, 256, 0, stream>>>(xbf, ln2w + l * TD, ln2b + l * TD, h);
        k_gemm256<3><<<gF1, 512, 131072, stream>>>(h, w1T, b1 + l * TDF, nullptr, ffa, nullptr, TM, TDF, TD);
        if (l + 1 < TL)
            k_gemm128d<5><<<gN1K, 512, 65536, stream>>>(ffa, w2T, b2 + l * TD, xbf, nullptr, xbf, TM, TD, TDF);
        else
            k_gemm128d<13><<<gN1K, 512, 65536, stream>>>(ffa, w2T, b2 + l * TD, xbf, xout, nullptr, TM, TD, TDF);
    }
    (void)in_sizes; (void)n_in; (void)out_size; (void)ws_size;
}